// Round 1
// baseline (575.555 us; speedup 1.0000x reference)
//
#include <hip/hip_runtime.h>

typedef unsigned short u16;
typedef __bf16 bf16x8 __attribute__((ext_vector_type(8)));
typedef float f32x4 __attribute__((ext_vector_type(4)));
typedef u16 u16x4 __attribute__((ext_vector_type(4)));

#define AS1P(p) ((__attribute__((address_space(1))) void*)(unsigned long long)(p))
#define AS3P(p) ((__attribute__((address_space(3))) void*)(unsigned long long)(p))
#define MFMA16(a, b, c) __builtin_amdgcn_mfma_f32_16x16x32_bf16((a), (b), (c), 0, 0, 0)

__device__ __forceinline__ u16 f2b(float x) { return __builtin_bit_cast(u16, (__bf16)x); }

// ---------------- elementwise f32 -> bf16 ----------------
__global__ __launch_bounds__(256) void cvt_f32_bf16(const float* __restrict__ in,
                                                    u16* __restrict__ out, int n4) {
  int stride = gridDim.x * blockDim.x;
  for (int i = blockIdx.x * blockDim.x + threadIdx.x; i < n4; i += stride) {
    f32x4 v = *(const f32x4*)(in + (long)i * 4);
    u16x4 o;
    o[0] = f2b(v[0]); o[1] = f2b(v[1]); o[2] = f2b(v[2]); o[3] = f2b(v[3]);
    *(u16x4*)(out + (long)i * 4) = o;
  }
}

// ---------------- weight transpose f32[K][N] -> bf16[N][K] ----------------
__global__ __launch_bounds__(256) void wtrans(const float* __restrict__ W,
                                              u16* __restrict__ Wt, int K, int N) {
  __shared__ float tile[32][33];
  int nbk = K >> 5;
  int bk = blockIdx.x % nbk;
  int bn = blockIdx.x / nbk;
  int tx = threadIdx.x & 31, ty = threadIdx.x >> 5;  // 32 x 8
#pragma unroll
  for (int i = 0; i < 32; i += 8)
    tile[ty + i][tx] = W[(long)(bk * 32 + ty + i) * N + bn * 32 + tx];
  __syncthreads();
#pragma unroll
  for (int i = 0; i < 32; i += 8)
    Wt[(long)(bn * 32 + ty + i) * K + bk * 32 + tx] = f2b(tile[tx][ty + i]);
}

// ---------------- v transpose bf16 [8][256][1024] -> [8][1024][256] ----------------
__global__ __launch_bounds__(256) void vtrans(const u16* __restrict__ v, u16* __restrict__ vt) {
  __shared__ u16 tile[32][33];
  int bt = blockIdx.x & 7;          // Se/32
  int bd = (blockIdx.x >> 3) & 31;  // D/32
  int bc = blockIdx.x >> 8;         // 8
  int tx = threadIdx.x & 31, ty = threadIdx.x >> 5;
  const long vb = (long)bc * 256 * 1024;
  const long ob = (long)bc * 1024 * 256;
#pragma unroll
  for (int i = 0; i < 32; i += 8)
    tile[ty + i][tx] = v[vb + (long)(bt * 32 + ty + i) * 1024 + bd * 32 + tx];
  __syncthreads();
#pragma unroll
  for (int i = 0; i < 32; i += 8)
    vt[ob + (long)(bd * 32 + ty + i) * 256 + bt * 32 + tx] = tile[tx][ty + i];
}

// ---------------- GEMM: C[M,N] = A[M,K] @ Bt[N,K]^T (bf16 in, MFMA 16x16x32) ----------
// MODE 0: write bf16 C.   MODE 1: write f32 C + bias[n] + resid[m*N+n] (final output).
template <int MODE>
__global__ __launch_bounds__(256) void gemm_bt(
    const u16* __restrict__ A, const u16* __restrict__ Bt,
    u16* __restrict__ outb, float* __restrict__ outf,
    const float* __restrict__ bias, const float* __restrict__ resid,
    int M, int N, int K) {
  __shared__ u16 lA[128 * 64];  // [row][k], 16B-slot XOR swizzled by (row&7)
  __shared__ u16 lB[128 * 64];
  const int tid = threadIdx.x;
  const int lane = tid & 63;
  const int wid = tid >> 6;
  const int wm = wid >> 1, wn = wid & 1;
  const int lr = lane & 15, lg = lane >> 4;

  const int nbn = N >> 7;
  const int bm = (int)blockIdx.x / nbn;
  const int bn = (int)blockIdx.x % nbn;
  const long arow0 = (long)bm * 128;
  const long brow0 = (long)bn * 128;

  f32x4 acc[4][4] = {};

  const int srow = tid >> 3;   // staging row within 32-row group
  const int scol = tid & 7;    // staging 16B slot

  for (int k0 = 0; k0 < K; k0 += 64) {
#pragma unroll
    for (int i = 0; i < 4; ++i) {
      int row = i * 32 + srow;
      int kc = scol ^ (row & 7);  // pre-swizzled global source
      __builtin_amdgcn_global_load_lds(AS1P(A + (arow0 + row) * K + k0 + kc * 8),
                                       AS3P(lA + i * 2048 + (tid & ~63) * 8), 16, 0, 0);
    }
#pragma unroll
    for (int i = 0; i < 4; ++i) {
      int row = i * 32 + srow;
      int kc = scol ^ (row & 7);
      __builtin_amdgcn_global_load_lds(AS1P(Bt + (brow0 + row) * K + k0 + kc * 8),
                                       AS3P(lB + i * 2048 + (tid & ~63) * 8), 16, 0, 0);
    }
    asm volatile("s_waitcnt vmcnt(0)" ::: "memory");
    __syncthreads();

#pragma unroll
    for (int ks = 0; ks < 2; ++ks) {
      bf16x8 af[4], bfr[4];
#pragma unroll
      for (int m = 0; m < 4; ++m) {
        int row = wm * 64 + m * 16 + lr;
        int off = row * 128 + ks * 64 + lg * 16;
        off ^= (row & 7) << 4;
        af[m] = *(const bf16x8*)((const char*)lA + off);
      }
#pragma unroll
      for (int n = 0; n < 4; ++n) {
        int row = wn * 64 + n * 16 + lr;
        int off = row * 128 + ks * 64 + lg * 16;
        off ^= (row & 7) << 4;
        bfr[n] = *(const bf16x8*)((const char*)lB + off);
      }
#pragma unroll
      for (int m = 0; m < 4; ++m)
#pragma unroll
        for (int n = 0; n < 4; ++n)
          acc[m][n] = MFMA16(af[m], bfr[n], acc[m][n]);
    }
    __syncthreads();
  }

  // epilogue: C/D layout row=(lane>>4)*4+r, col=lane&15
#pragma unroll
  for (int m = 0; m < 4; ++m) {
#pragma unroll
    for (int n = 0; n < 4; ++n) {
      long col = brow0 + wn * 64 + n * 16 + lr;
#pragma unroll
      for (int r = 0; r < 4; ++r) {
        long row = arow0 + wm * 64 + m * 16 + lg * 4 + r;
        float v = acc[m][n][r];
        if (MODE == 0) {
          outb[row * N + col] = f2b(v);
        } else {
          long idx = row * N + col;
          outf[idx] = v + bias[col] + resid[idx];
        }
      }
    }
  }
}

// ---------------- fused decomposing attention ----------------
// grid: b(2) x h(16) x sblk(64); block 256 = 4 waves x 16 s-rows.
// Per wave: all 4 components' scores held in-lane -> component softmax is pure VALU.
__global__ __launch_bounds__(256) void attn_fused(
    const u16* __restrict__ q,   // [BC][S][D] bf16
    const u16* __restrict__ k,   // [BC][Se][D] bf16
    const u16* __restrict__ vt,  // [BC][D][Se] bf16
    u16* __restrict__ attn,      // [BC][S][D] bf16
    float* __restrict__ ent) {   // [B][H][S][Se] f32
  const int B = 2, H = 16, S = 4096, Se = 256, D = 1024;
  __shared__ u16 ldsK[16384];  // [c][64 t][64 dh] swizzled; reused as P after QK^T
  __shared__ u16 ldsV[16384];  // [c][64 dh][64 t] swizzled
  const int tid = threadIdx.x;
  const int lane = tid & 63, wid = tid >> 6;
  const int lr = lane & 15, lg = lane >> 4;
  const int sblk = blockIdx.x & 63;
  const int h = (blockIdx.x >> 6) & 15;
  const int b = blockIdx.x >> 10;
  const int s0 = sblk * 64 + wid * 16;
  const int srow = tid >> 3, scol = tid & 7;

  // hoist Q fragments (A-frag: row=lr, k=(lg*8 + ks*32))
  bf16x8 qf[4][2];
#pragma unroll
  for (int c = 0; c < 4; ++c)
#pragma unroll
    for (int ks = 0; ks < 2; ++ks)
      qf[c][ks] = *(const bf16x8*)(q + ((c * B + b) * (long)S + s0 + lr) * D + h * 64 + ks * 32 + lg * 8);

  f32x4 oacc[4][4] = {};  // [c][dh-subtile]

  for (int tc = 0; tc < 4; ++tc) {
    // ---- stage K,V chunk for all 4 components (coalesced, pre-swizzled source)
#pragma unroll
    for (int i = 0; i < 8; ++i) {
      int c = i >> 1;
      int trow = (i & 1) * 32 + srow;
      int kc = scol ^ (trow & 7);
      __builtin_amdgcn_global_load_lds(
          AS1P(k + ((c * B + b) * (long)Se + tc * 64 + trow) * D + h * 64 + kc * 8),
          AS3P(ldsK + i * 2048 + (tid & ~63) * 8), 16, 0, 0);
    }
#pragma unroll
    for (int i = 0; i < 8; ++i) {
      int c = i >> 1;
      int drow = (i & 1) * 32 + srow;
      int kc = scol ^ (drow & 7);
      __builtin_amdgcn_global_load_lds(
          AS1P(vt + ((c * B + b) * (long)D + h * 64 + drow) * Se + tc * 64 + kc * 8),
          AS3P(ldsV + i * 2048 + (tid & ~63) * 8), 16, 0, 0);
    }
    asm volatile("s_waitcnt vmcnt(0)" ::: "memory");
    __syncthreads();

    // ---- QK^T for the 4 components
    f32x4 sacc[4][4] = {};  // [c][t-subtile]
#pragma unroll
    for (int c = 0; c < 4; ++c) {
#pragma unroll
      for (int ts = 0; ts < 4; ++ts) {
#pragma unroll
        for (int ks = 0; ks < 2; ++ks) {
          int trow = ts * 16 + lr;
          int off = c * 8192 + trow * 128 + ks * 64 + lg * 16;
          off ^= (trow & 7) << 4;
          bf16x8 kf = *(const bf16x8*)((const char*)ldsK + off);
          sacc[c][ts] = MFMA16(qf[c][ks], kf, sacc[c][ts]);
        }
      }
    }
    __syncthreads();  // all waves done reading K; its space becomes per-wave P

    // ---- in-lane component softmax + entropy + P write (P = ldsK + wid*8KB)
    u16* P = ldsK + wid * 4096;  // 4096 u16 = 8KB per wave: [c][16][64]
#pragma unroll
    for (int ts = 0; ts < 4; ++ts) {
#pragma unroll
      for (int r = 0; r < 4; ++r) {
        float v0 = sacc[0][ts][r] * 0.125f;
        float v1 = sacc[1][ts][r] * 0.125f;
        float v2 = sacc[2][ts][r] * 0.125f;
        float v3 = sacc[3][ts][r] * 0.125f;
        float mx = fmaxf(fmaxf(v0, v1), fmaxf(v2, v3));
        float e0 = __expf(v0 - mx), e1 = __expf(v1 - mx);
        float e2 = __expf(v2 - mx), e3 = __expf(v3 - mx);
        float sum = e0 + e1 + e2 + e3;
        float inv = 1.0f / sum;
        float lse = __logf(sum);
        float w0 = e0 * inv, w1 = e1 * inv, w2 = e2 * inv, w3 = e3 * inv;
        float entv = w0 * (v0 - mx - lse) + w1 * (v1 - mx - lse) +
                     w2 * (v2 - mx - lse) + w3 * (v3 - mx - lse);
        int s = s0 + lg * 4 + r;
        int t = tc * 64 + ts * 16 + lr;
        ent[((b * H + h) * (long)S + s) * Se + t] = entv;
        int prow = lg * 4 + r;
        int off = prow * 128 + (ts * 16 + lr) * 2;
        off ^= (prow & 7) << 4;
        const float rs = 1.0f / 64.0f;  // C/Se
        *(u16*)((char*)P + 0 * 2048 + off) = f2b(w0 * rs);
        *(u16*)((char*)P + 1 * 2048 + off) = f2b(w1 * rs);
        *(u16*)((char*)P + 2 * 2048 + off) = f2b(w2 * rs);
        *(u16*)((char*)P + 3 * 2048 + off) = f2b(w3 * rs);
      }
    }

    // ---- PV
#pragma unroll
    for (int c = 0; c < 4; ++c) {
      bf16x8 pf[2];
#pragma unroll
      for (int ks = 0; ks < 2; ++ks) {
        int off = lr * 128 + ks * 64 + lg * 16;
        off ^= (lr & 7) << 4;
        pf[ks] = *(const bf16x8*)((const char*)P + c * 2048 + off);
      }
#pragma unroll
      for (int dsu = 0; dsu < 4; ++dsu) {
#pragma unroll
        for (int ks = 0; ks < 2; ++ks) {
          int drow = dsu * 16 + lr;
          int off = c * 8192 + drow * 128 + ks * 64 + lg * 16;
          off ^= (drow & 7) << 4;
          bf16x8 vf = *(const bf16x8*)((const char*)ldsV + off);
          oacc[c][dsu] = MFMA16(pf[ks], vf, oacc[c][dsu]);
        }
      }
    }
    __syncthreads();  // protect ldsK(P)/ldsV before next stage
  }

  // ---- epilogue: write attn out bf16
#pragma unroll
  for (int c = 0; c < 4; ++c)
#pragma unroll
    for (int dsu = 0; dsu < 4; ++dsu)
#pragma unroll
      for (int r = 0; r < 4; ++r) {
        int s = s0 + lg * 4 + r;
        attn[((c * B + b) * (long)S + s) * D + h * 64 + dsu * 16 + lr] = f2b(oacc[c][dsu][r]);
      }
}

extern "C" void kernel_launch(void* const* d_in, const int* in_sizes, int n_in,
                              void* d_out, int out_size, void* d_ws, size_t ws_size,
                              hipStream_t stream) {
  const float* hs  = (const float*)d_in[0];  // [8,4096,1024]
  const float* ehs = (const float*)d_in[1];  // [8,256,2048]
  const float* Wq  = (const float*)d_in[2];  // [1024,1024]
  const float* Wk  = (const float*)d_in[3];  // [2048,1024]
  const float* Wv  = (const float*)d_in[4];  // [2048,1024]
  const float* Wo  = (const float*)d_in[5];  // [1024,1024]
  const float* bo  = (const float*)d_in[6];  // [1024]
  float* out = (float*)d_out;
  float* ent = out + (size_t)8 * 4096 * 1024;

  char* ws = (char*)d_ws;
  u16* hsb  = (u16*)(ws);              // 67,108,864 B (bf16 hs; later reused as attn out)
  u16* ehsb = (u16*)(ws + 67108864);   //  8,388,608 B
  u16* wqT  = (u16*)(ws + 75497472);   //  2,097,152 B
  u16* wkT  = (u16*)(ws + 77594624);   //  4,194,304 B
  u16* wvT  = (u16*)(ws + 81788928);   //  4,194,304 B
  u16* woT  = (u16*)(ws + 85983232);   //  2,097,152 B
  u16* qb   = (u16*)(ws + 88080384);   // 67,108,864 B
  u16* kb   = (u16*)(ws + 155189248);  //  4,194,304 B
  u16* vtmp = (u16*)(ws + 159383552);  //  4,194,304 B
  u16* vtb  = (u16*)(ws + 163577856);  //  4,194,304 B  (end: 167,772,160)

  cvt_f32_bf16<<<2048, 256, 0, stream>>>(hs, hsb, (8 * 4096 * 1024) / 4);
  cvt_f32_bf16<<<512, 256, 0, stream>>>(ehs, ehsb, (8 * 256 * 2048) / 4);
  wtrans<<<1024, 256, 0, stream>>>(Wq, wqT, 1024, 1024);
  wtrans<<<2048, 256, 0, stream>>>(Wk, wkT, 2048, 1024);
  wtrans<<<2048, 256, 0, stream>>>(Wv, wvT, 2048, 1024);
  wtrans<<<1024, 256, 0, stream>>>(Wo, woT, 1024, 1024);
  // q = hs @ Wq
  gemm_bt<0><<<(32768 / 128) * (1024 / 128), 256, 0, stream>>>(
      hsb, wqT, qb, nullptr, nullptr, nullptr, 32768, 1024, 1024);
  // k = ehs @ Wk
  gemm_bt<0><<<(2048 / 128) * (1024 / 128), 256, 0, stream>>>(
      ehsb, wkT, kb, nullptr, nullptr, nullptr, 2048, 1024, 2048);
  // v = ehs @ Wv
  gemm_bt<0><<<(2048 / 128) * (1024 / 128), 256, 0, stream>>>(
      ehsb, wvT, vtmp, nullptr, nullptr, nullptr, 2048, 1024, 2048);
  vtrans<<<2048, 256, 0, stream>>>(vtmp, vtb);
  // fused component-softmax attention (writes attn into hsb region + entropy to d_out)
  attn_fused<<<2048, 256, 0, stream>>>(qb, kb, vtb, hsb, ent);
  // out = attn @ Wo + bo + hs
  gemm_bt<1><<<(32768 / 128) * (1024 / 128), 256, 0, stream>>>(
      hsb, woT, nullptr, out, bo, hs, 32768, 1024, 1024);
}